// Round 11
// baseline (3551.335 us; speedup 1.0000x reference)
//
#include <hip/hip_runtime.h>

#define LSEQ 2048
#define TAGS 12

typedef _Float16 half2v __attribute__((ext_vector_type(2)));
typedef unsigned long long u64;

__device__ __forceinline__ float sigm(float x){ return 1.0f/(1.0f+__expf(-x)); }
__device__ __forceinline__ float tanh_fast(float x){ return 1.0f - 2.0f/(1.0f+__expf(2.0f*x)); }
__device__ __forceinline__ half2v pack2(float a, float b){
  half2v r; r.x=(_Float16)a; r.y=(_Float16)b; return r;
}

// K1: xg[d][t][row] = b_ih[row]+b_hh[row] + sum_e embed[sent[t]][e]*w_ih[row][e]
// Block 0 also zeroes the exchange buffer (ordering: xg completes before lstm).
__global__ void xg_kernel(
    const int* sent, const float* embed,
    const float* w_ih_f, const float* b_ih_f, const float* b_hh_f,
    const float* w_ih_b, const float* b_ih_b, const float* b_hh_b,
    float* xg, u64* ex)
{
  __shared__ float x_sh[8][256];
  int tid = threadIdx.x;
  if (blockIdx.x == 0){
    #pragma unroll
    for (int i=0;i<4;++i) ex[tid + 256*i] = 0ull;   // tag 0 never matches [1,2048]
  }
  int t0 = blockIdx.x * 8;
  for (int i=0;i<8;++i){
    int idx = sent[t0+i];
    x_sh[i][tid] = embed[(size_t)idx*256 + tid];
  }
  __syncthreads();
  for (int ri=0; ri<8; ++ri){
    int r = ri*256 + tid;
    int d = r >> 10;
    int row = r & 1023;
    const float* wr = (d ? w_ih_b : w_ih_f) + (size_t)row*256;
    const float* bi = d ? b_ih_b : b_ih_f;
    const float* bh = d ? b_hh_b : b_hh_f;
    float acc[8];
    #pragma unroll
    for (int i=0;i<8;++i) acc[i]=0.f;
    for (int k0=0;k0<256;k0+=4){
      float4 p = *(const float4*)(wr + k0);
      #pragma unroll
      for (int i=0;i<8;++i){
        acc[i] += p.x*x_sh[i][k0] + p.y*x_sh[i][k0+1]
                + p.z*x_sh[i][k0+2] + p.w*x_sh[i][k0+3];
      }
    }
    float bias = bi[row] + bh[row];
    #pragma unroll
    for (int i=0;i<8;++i)
      xg[((size_t)d*LSEQ + (size_t)(t0+i))*1024 + row] = acc[i] + bias;
  }
}

// K2: bidirectional LSTM recurrence, 4 CUs/direction, spill-free (~150 VGPR).
// Round-11 structure: own-h pair lives in a REGISTER (hl) -- every thread
// redundantly computes its own pair's (c,h) update (deterministic, replicas
// agree), killing the 3rd barrier and the own-h LDS round-trip. Remote h
// arrives via ds_read_b128 broadcast (96 pairs = 24 reads, direct to VGPRs;
// replaces 96 readlane+mov). Sender publishes h immediately at end of update
// via agent-scope atomic store; pollers (waves 1-2, vmcnt-independent from
// senders in wave 0) pre-issue their probe before the local dot.
__global__ __launch_bounds__(256,1) void lstm_rec(
    const float* __restrict__ w_hh_f, const float* __restrict__ w_hh_b,
    const float* __restrict__ xg, unsigned short* __restrict__ hstH,
    u64* __restrict__ ex)
{
  int blk = blockIdx.x;
  int d = blk & 7;
  if (d > 1) return;
  int q = blk >> 3;                 // quad: owns units [64q, 64q+64)
  int qa = (q+1)&3, qb = (q+2)&3, qc = (q+3)&3;

  int tid = threadIdx.x;
  int g = tid >> 6, l = tid & 63;
  int m = l & 31;                   // own pair index (CU-local)
  int row = g*256 + 64*q + l;       // gate row (PyTorch order i,f,g,o)
  const float* W = d ? w_hh_b : w_hh_f;
  const float* xgd = xg + (size_t)d*LSEQ*1024;
  unsigned short* hd = hstH + (size_t)d*LSEQ*256;
  u64* exd = ex + (size_t)d*256;    // [2 parity][128 pairs]

  __shared__ float gate_sh[256];              // [gate][64 units]
  __shared__ __align__(16) unsigned h2rem[96];// remote pairs: qa|qb|qc sections

  // Permuted-column weights: w[0..31]=own pairs, then peers qa, qb, qc.
  half2v w[128];
  {
    const float* p0 = W + (size_t)row*256 + 64*q;
    const float* p1 = W + (size_t)row*256 + 64*qa;
    const float* p2 = W + (size_t)row*256 + 64*qb;
    const float* p3 = W + (size_t)row*256 + 64*qc;
    #pragma unroll
    for (int k0=0;k0<16;++k0){
      float4 a = *(const float4*)(p0+4*k0);
      w[2*k0]      = pack2(a.x,a.y);  w[2*k0+1]    = pack2(a.z,a.w);
      float4 b = *(const float4*)(p1+4*k0);
      w[32+2*k0]   = pack2(b.x,b.y);  w[32+2*k0+1] = pack2(b.z,b.w);
      float4 cc= *(const float4*)(p2+4*k0);
      w[64+2*k0]   = pack2(cc.x,cc.y); w[64+2*k0+1] = pack2(cc.z,cc.w);
      float4 e = *(const float4*)(p3+4*k0);
      w[96+2*k0]   = pack2(e.x,e.y);  w[96+2*k0+1] = pack2(e.z,e.w);
    }
  }
  if (tid < 96) h2rem[tid] = 0u;
  float c0 = 0.f, c1 = 0.f;         // replicated cell state for pair m
  unsigned hl = 0u;                 // own h-pair register (replicated)

  // loop-invariant poller mapping: threads 64..159 poll the 96 remote slots
  int pollj = tid - 64;                         // 0..95 when poller
  int pollpeer = (q + 1 + (pollj>>5)) & 3;
  int pollslot = 32*pollpeer + (pollj & 31);    // index into exd parity block
  bool isPoller = (tid >= 64) && (tid < 160);
  __syncthreads();

  int tf = d ? (LSEQ-1) : 0;
  float xg0 = xgd[(size_t)tf*1024 + row];

  for (int s=0;s<LSEQ;++s){
    // --- pollers: pre-issue probe (hides under local dot)
    u64 v0 = 0ull;
    bool poll = (s > 0) && isPoller;
    if (poll)
      v0 = __hip_atomic_load(&exd[((s&1)<<7) + pollslot],
                             __ATOMIC_RELAXED, __HIP_MEMORY_SCOPE_AGENT);
    // --- local quarter dot from the hl registers (readlane broadcast)
    float a0=xg0, a1=0.f, a2=0.f, a3=0.f;
    #pragma unroll
    for (int k=0;k<32;k+=4){
      unsigned p0v = __builtin_amdgcn_readlane(hl,k);
      unsigned p1v = __builtin_amdgcn_readlane(hl,k+1);
      unsigned p2v = __builtin_amdgcn_readlane(hl,k+2);
      unsigned p3v = __builtin_amdgcn_readlane(hl,k+3);
      a0 = __builtin_amdgcn_fdot2(__builtin_bit_cast(half2v,p0v), w[k],   a0, false);
      a1 = __builtin_amdgcn_fdot2(__builtin_bit_cast(half2v,p1v), w[k+1], a1, false);
      a2 = __builtin_amdgcn_fdot2(__builtin_bit_cast(half2v,p2v), w[k+2], a2, false);
      a3 = __builtin_amdgcn_fdot2(__builtin_bit_cast(half2v,p3v), w[k+3], a3, false);
    }
    // --- finish poll, stash remote pairs in LDS
    if (poll){
      u64 v = v0;
      while ((unsigned)(v>>32) != (unsigned)s)
        v = __hip_atomic_load(&exd[((s&1)<<7) + pollslot],
                              __ATOMIC_RELAXED, __HIP_MEMORY_SCOPE_AGENT);
      h2rem[pollj] = (unsigned)v;
    }
    // --- prefetch next xg (after poll; consumed only at next step's dot)
    float nxg = 0.f;
    if (s+1 < LSEQ){
      int tn = d ? (LSEQ-2-s) : (s+1);
      nxg = xgd[(size_t)tn*1024 + row];
    }
    __syncthreads();   // barrier A: h2rem ready
    // --- remote 3/4 dot: 24 uniform-address b128 broadcasts -> 96 fdot2
    #pragma unroll
    for (int j=0;j<24;++j){
      uint4 hv = *(const uint4*)&h2rem[4*j];
      a0 = __builtin_amdgcn_fdot2(__builtin_bit_cast(half2v,hv.x), w[32+4*j],   a0, false);
      a1 = __builtin_amdgcn_fdot2(__builtin_bit_cast(half2v,hv.y), w[32+4*j+1], a1, false);
      a2 = __builtin_amdgcn_fdot2(__builtin_bit_cast(half2v,hv.z), w[32+4*j+2], a2, false);
      a3 = __builtin_amdgcn_fdot2(__builtin_bit_cast(half2v,hv.w), w[32+4*j+3], a3, false);
    }
    float pre = (a0+a1) + (a2+a3);
    float act = (g==2) ? tanh_fast(pre) : sigm(pre);
    gate_sh[tid] = act;               // [g][64]: tid = g*64 + l
    xg0 = nxg;
    __syncthreads();   // barrier B: gates ready
    // --- redundant update: EVERY thread computes its pair m's (c,h)
    {
      float2 gi = *(const float2*)&gate_sh[      2*m];
      float2 gf = *(const float2*)&gate_sh[ 64 + 2*m];
      float2 gg = *(const float2*)&gate_sh[128 + 2*m];
      float2 go = *(const float2*)&gate_sh[192 + 2*m];
      c0 = gf.x*c0 + gi.x*gg.x;
      c1 = gf.y*c1 + gi.y*gg.y;
      float h0 = go.x * tanh_fast(c0);
      float h1 = go.y * tanh_fast(c1);
      hl = __builtin_bit_cast(unsigned, pack2(h0,h1));
    }
    // --- publish immediately (wave 0 lanes 0..31; vmcnt-private to wave 0)
    if (tid < 32){
      if (s+1 < LSEQ)
        __hip_atomic_store(&exd[(((s+1)&1)<<7) + 32*q + tid],
                           ((u64)(unsigned)(s+1) << 32) | (u64)hl,
                           __ATOMIC_RELAXED, __HIP_MEMORY_SCOPE_AGENT);
      int tp = d ? (LSEQ-1-s) : s;
      *(unsigned*)&hd[(size_t)tp*256 + 64*q + 2*tid] = hl;
    }
    // no third barrier: next local dot reads hl (register); gate_sh/h2rem
    // rewrites happen only after the next barrier A.
  }
}

// K3: feats[t][tag] = b_out[tag] + [hf|hb] . w_out[tag]   (h history is f16)
__global__ void feats_kernel(
    const unsigned short* hstH, const float* w_out, const float* b_out,
    float* feats)
{
  __shared__ float w_sh[12*520];
  __shared__ float h_sh[16*520];
  const _Float16* hf = (const _Float16*)hstH;
  int tid=threadIdx.x;
  int t0=blockIdx.x*16;
  for (int i=tid;i<12*512;i+=256){ int tag=i>>9,k=i&511; w_sh[tag*520+k]=w_out[i]; }
  for (int i=tid;i<16*512;i+=256){
    int tt=i>>9,k=i&511;
    float v = (k<256)? (float)hf[(size_t)(t0+tt)*256+k]
                     : (float)hf[(size_t)(LSEQ+t0+tt)*256 + (k-256)];
    h_sh[tt*520+k]=v;
  }
  __syncthreads();
  if (tid<192){
    int tt=tid/12, tag=tid%12;
    const float* wr=&w_sh[tag*520];
    const float* hr=&h_sh[tt*520];
    float acc=b_out[tag];
    for (int k=0;k<512;k+=4){
      float4 a=*(const float4*)(wr+k);
      float4 b=*(const float4*)(hr+k);
      acc += a.x*b.x+a.y*b.y+a.z*b.z+a.w*b.w;
    }
    feats[(size_t)(t0+tt)*12+tag]=acc;
  }
}

// K4: Viterbi DP: feats in LDS, v register-resident via readlane; parallel
// block-composed backtrack.
__global__ void BiLSTM_CRF_14405320311361_kernel(
    const float* feats, const float* trans, float* outp)
{
  __shared__ float fsh[LSEQ*12];           // 96 KB
  __shared__ unsigned char bps[LSEQ*12];   // 24 KB
  __shared__ float term_sh[16];
  __shared__ int ibuf[66];
  __shared__ unsigned char fmap[64*12];
  int tid = threadIdx.x;
  for (int i=tid; i<LSEQ*12/4; i+=256)
    *(float4*)&fsh[4*i] = *(const float4*)&feats[4*i];
  __syncthreads();

  int lane = tid & 63;
  int fl = (lane<12) ? lane : 0;
  float vn = 0.f;
  if (tid < 64){
    float tr[12];
    #pragma unroll
    for (int p=0;p<12;++p) tr[p] = trans[fl*12+p];
    vn = (lane==10) ? 0.f : -10000.f;     // START=10
    float fa = fsh[fl];
    float fb = fsh[12+fl];
    for (int t=0;t<LSEQ;++t){
      unsigned vu = __float_as_uint(vn);
      float best; int bp; float sc;
      best = tr[0] + __uint_as_float(__builtin_amdgcn_readlane(vu,0)); bp = 0;
      sc = tr[1]  + __uint_as_float(__builtin_amdgcn_readlane(vu,1));  if(sc>best){best=sc;bp=1;}
      sc = tr[2]  + __uint_as_float(__builtin_amdgcn_readlane(vu,2));  if(sc>best){best=sc;bp=2;}
      sc = tr[3]  + __uint_as_float(__builtin_amdgcn_readlane(vu,3));  if(sc>best){best=sc;bp=3;}
      sc = tr[4]  + __uint_as_float(__builtin_amdgcn_readlane(vu,4));  if(sc>best){best=sc;bp=4;}
      sc = tr[5]  + __uint_as_float(__builtin_amdgcn_readlane(vu,5));  if(sc>best){best=sc;bp=5;}
      sc = tr[6]  + __uint_as_float(__builtin_amdgcn_readlane(vu,6));  if(sc>best){best=sc;bp=6;}
      sc = tr[7]  + __uint_as_float(__builtin_amdgcn_readlane(vu,7));  if(sc>best){best=sc;bp=7;}
      sc = tr[8]  + __uint_as_float(__builtin_amdgcn_readlane(vu,8));  if(sc>best){best=sc;bp=8;}
      sc = tr[9]  + __uint_as_float(__builtin_amdgcn_readlane(vu,9));  if(sc>best){best=sc;bp=9;}
      sc = tr[10] + __uint_as_float(__builtin_amdgcn_readlane(vu,10)); if(sc>best){best=sc;bp=10;}
      sc = tr[11] + __uint_as_float(__builtin_amdgcn_readlane(vu,11)); if(sc>best){best=sc;bp=11;}
      vn = best + fa;
      fa = fb;
      if (t+2 < LSEQ) fb = fsh[(t+2)*12+fl];
      if (lane<12) bps[t*12+lane] = (unsigned char)bp;
    }
  }
  if (tid < 12) term_sh[tid] = vn + trans[11*12+tid];   // STOP=11
  __syncthreads();
  if (tid == 0){
    float bs=term_sh[0]; int bt=0;
    for (int p=1;p<12;++p){ if (term_sh[p]>bs){bs=term_sh[p];bt=p;} }
    outp[0] = bs;
    ibuf[64] = bt;
  }
  __syncthreads();
  if (tid < 64){
    int b = tid;
    int f[12];
    int thi = b*32+31;
    #pragma unroll
    for (int x=0;x<12;++x) f[x] = bps[thi*12+x];
    for (int t=thi-1; t>=b*32; --t){
      int base = t*12;
      #pragma unroll
      for (int x=0;x<12;++x) f[x] = bps[base + f[x]];
    }
    #pragma unroll
    for (int x=0;x<12;++x) fmap[b*12+x] = (unsigned char)f[x];
  }
  __syncthreads();
  if (tid == 0){
    int tag = ibuf[64];
    for (int b=63;b>=0;--b){ ibuf[b]=tag; tag = fmap[b*12+tag]; }
  }
  __syncthreads();
  if (tid < 64){
    int b = tid;
    int tag = ibuf[b];
    for (int t=b*32+31; t>=b*32; --t){
      outp[1+t] = (float)tag;
      tag = bps[t*12+tag];
    }
  }
}

extern "C" void kernel_launch(void* const* d_in, const int* in_sizes, int n_in,
                              void* d_out, int out_size, void* d_ws, size_t ws_size,
                              hipStream_t stream) {
  const int*   sent   = (const int*)d_in[0];
  const float* embed  = (const float*)d_in[1];
  const float* w_ih_f = (const float*)d_in[2];
  const float* w_hh_f = (const float*)d_in[3];
  const float* b_ih_f = (const float*)d_in[4];
  const float* b_hh_f = (const float*)d_in[5];
  const float* w_ih_b = (const float*)d_in[6];
  const float* w_hh_b = (const float*)d_in[7];
  const float* b_ih_b = (const float*)d_in[8];
  const float* b_hh_b = (const float*)d_in[9];
  const float* w_out  = (const float*)d_in[10];
  const float* b_out  = (const float*)d_in[11];
  const float* trans  = (const float*)d_in[12];

  float* xg = (float*)d_ws;                                           // [2][L][1024] f32 = 16 MB
  unsigned short* hstH = (unsigned short*)(xg + (size_t)2*LSEQ*1024); // [2][L][256] f16 = 2 MB
  u64* ex = (u64*)(hstH + (size_t)2*LSEQ*256);                        // 8 KB
  float* feats = (float*)(ex + 1024);                                 // [L][12] f32 = 96 KB
  float* outp  = (float*)d_out;

  xg_kernel<<<dim3(LSEQ/8), dim3(256), 0, stream>>>(
      sent, embed, w_ih_f, b_ih_f, b_hh_f, w_ih_b, b_ih_b, b_hh_b, xg, ex);
  lstm_rec<<<dim3(32), dim3(256), 0, stream>>>(w_hh_f, w_hh_b, xg, hstH, ex);
  feats_kernel<<<dim3(LSEQ/16), dim3(256), 0, stream>>>(hstH, w_out, b_out, feats);
  BiLSTM_CRF_14405320311361_kernel<<<dim3(1), dim3(256), 0, stream>>>(feats, trans, outp);
}